// Round 9
// baseline (52.237 us; speedup 1.0000x reference)
//
#include <hip/hip_runtime.h>
#include <hip/hip_fp16.h>

#define NN   512
#define D    128      // INPUT_DIM
#define HID  256      // HIDDEN_DIM
#define REL  128      // REL_DIM
#define ODIM 64

typedef __attribute__((ext_vector_type(4)))  float    f32x4;
typedef __attribute__((ext_vector_type(16))) float    f32x16;
typedef __attribute__((ext_vector_type(8)))  _Float16 f16x8;

// ---------------- kAW: blocks 0..127 compute A'(fp16, row-major) and B (fp16, frag-major Bg);
//                  blocks 128..143 pack W2 into 32x32x16 B-fragment order (W2g).
// Bg layout: [jt(32)][ks(16)][hs(2)][j(16)][e(8)]  (8 KB per jt, contiguous)
// W2g layout: frag f = cg*16+ks: [f][lane(64)][e(8)], elem = W2[ks*16+(l>>5)*8+e][cg*32+(l&31)]
__global__ void kAW(const float* __restrict__ X, const float* __restrict__ W1,
                    const float* __restrict__ b1, _Float16* __restrict__ Aph,
                    _Float16* __restrict__ Bg,
                    const float* __restrict__ W2, _Float16* __restrict__ W2g) {
    int t = threadIdx.x;            // 0..255
    if (blockIdx.x >= 128) {        // ---- W2 pack
        int gid = (blockIdx.x - 128) * 256 + t;   // 0..4095
        int f = gid >> 6, l = gid & 63;
        int cg = f >> 4, ks = f & 15;
        f16x8 pkd;
#pragma unroll
        for (int e = 0; e < 8; ++e) {
            int k = ks * 16 + (l >> 5) * 8 + e;
            int c = cg * 32 + (l & 31);
            pkd[e] = (_Float16)W2[k * REL + c];
        }
        *(f16x8*)&W2g[(size_t)gid * 8] = pkd;
        return;
    }
    __shared__ float Xs[4][D];
    int r0 = blockIdx.x * 4;
#pragma unroll
    for (int q = 0; q < 2; ++q) {
        int idx = q * 256 + t;
        Xs[idx >> 7][idx & 127] = X[(r0 + (idx >> 7)) * D + (idx & 127)];
    }
    __syncthreads();
    float a[4], b[4];
    float b1c = b1[t];
#pragma unroll
    for (int r = 0; r < 4; ++r) { a[r] = b1c; b[r] = 0.f; }
#pragma unroll 4
    for (int k = 0; k < D; ++k) {
        float wt = W1[k * HID + t];
        float wb = W1[(D + k) * HID + t];
#pragma unroll
        for (int r = 0; r < 4; ++r) {
            a[r] += Xs[r][k] * wt;
            b[r] += Xs[r][k] * wb;
        }
    }
    int ks = t >> 4, hs = (t >> 3) & 1, e = t & 7;
#pragma unroll
    for (int r = 0; r < 4; ++r) {
        int row = r0 + r;
        Aph[row * HID + t] = (_Float16)a[r];
        Bg[(row >> 4) * 4096 + ks * 256 + hs * 128 + (row & 15) * 8 + e] = (_Float16)b[r];
    }
}

// ---------------- kB: 32x32x16 MFMA pair GEMM, all-register, spill-free budget.
// 512 blocks (2/CU), 4 waves. blk = it(2b)<<7 | ch(2b)<<5 | jt(5b).
// Block covers: rows it*128..+128 (16 units x 8), cols ch*32..+32, j-tile jt (16 j).
// Wave = 32 pairs (2i x 16j). w2r (64 VGPR) + brow (64) + af (64) + acc (16) ~= 230 VGPR.
__global__ __launch_bounds__(256, 2) void kB(const _Float16* __restrict__ Aph,
                                             const _Float16* __restrict__ Bg,
                                             const _Float16* __restrict__ W2g,
                                             const float* __restrict__ b2,
                                             float* __restrict__ partial) {
    __shared__ float redsh[4][32];

    int t = threadIdx.x, w = t >> 6, l = t & 63;
    int blk = blockIdx.x;
    int jt = blk & 31, ch = (blk >> 5) & 3, it = blk >> 7;
    int i_base = it * 128;
    int l31 = l & 31, hs = l >> 5, j = l & 15;
    int i_off = 2 * w + (l31 >> 4);      // this lane's row within an 8-row unit

    // W2 fragments: this block's 32-col group, 16 k-steps (64 VGPR), loaded once
    f16x8 w2r[16];
#pragma unroll
    for (int ks = 0; ks < 16; ++ks)
        w2r[ks] = *(const f16x8*)&W2g[(size_t)((ch * 16 + ks) * 64 + l) * 8];

    // B fragments for this lane's (j, hs): 16 k-steps (64 VGPR), block-constant
    f16x8 brow[16];
#pragma unroll
    for (int ks = 0; ks < 16; ++ks)
        brow[ks] = *(const f16x8*)&Bg[(size_t)jt * 4096 + ks * 256 + hs * 128 + j * 8];

    float b2c = b2[ch * 32 + l31];
    float psum = 0.f;

#pragma unroll 1
    for (int u = 0; u < 16; ++u) {
        const _Float16* arow = &Aph[(i_base + u * 8 + i_off) * HID + hs * 8];

        // batch the 16 A-fragment loads (4 distinct 16B addrs per instr, L2-resident)
        f16x8 af[16];
#pragma unroll
        for (int ks = 0; ks < 16; ++ks)
            af[ks] = *(const f16x8*)(arow + ks * 16);

        f32x16 acc;
#pragma unroll
        for (int r = 0; r < 16; ++r) acc[r] = 0.f;

#pragma unroll
        for (int ks = 0; ks < 16; ++ks) {
            f16x8 sum = af[ks] + brow[ks];                                  // v_pk_add_f16 x4
            f16x8 h = __builtin_elementwise_max(sum, (f16x8)(_Float16)0.f); // v_pk_max_f16 x4
            acc = __builtin_amdgcn_mfma_f32_32x32x16_f16(h, w2r[ks], acc, 0, 0, 0);
        }

        // per-unit epilogue: relu(acc + b2), sum over this lane's 16 pair-rows
        float s0 = 0.f;
#pragma unroll
        for (int r = 0; r < 16; ++r) s0 += fmaxf(acc[r] + b2c, 0.f);
        psum += s0;
    }

    // column sum: lanes l and l+32 hold complementary row-halves of the same column
    psum += __shfl_xor(psum, 32);
    if (l < 32) redsh[w][l] = psum;
    __syncthreads();
    if (w == 0 && l < 32)
        partial[blk * 32 + l] = redsh[0][l] + redsh[1][l] + redsh[2][l] + redsh[3][l];
}

// ---------------- kRC: reduce 512 per-block partials -> R (mean), then final tiny MLP
// Block blk = it*128 + ch*32 + jt holds cols [ch*32, ch*32+32).
__global__ void kRC(const float* __restrict__ partial,
                    const float* __restrict__ W3, const float* __restrict__ b3,
                    const float* __restrict__ W4, const float* __restrict__ b4,
                    float* __restrict__ out) {
    __shared__ float sh[256];
    __shared__ float Rsh[REL];
    __shared__ float t1[ODIM];
    int t = threadIdx.x;                 // 256
    int c = t & 127, g = t >> 7;
    int ch = c >> 5, cc = c & 31;
    float s = 0.f;
#pragma unroll 4
    for (int q = g * 64; q < g * 64 + 64; ++q) {    // q = it*32 + jt (half-range per g)
        int itq = q >> 5, jtq = q & 31;
        int blk = itq * 128 + ch * 32 + jtq;
        s += partial[blk * 32 + cc];
    }
    sh[t] = s;
    __syncthreads();
    if (t < 128) Rsh[t] = (sh[t] + sh[t + 128]) * (1.f / 262144.f);
    __syncthreads();
    if (t < ODIM) {
        float s3 = b3[t];
#pragma unroll 8
        for (int k = 0; k < REL; ++k) s3 += Rsh[k] * W3[k * ODIM + t];
        t1[t] = fmaxf(s3, 0.f);
    }
    __syncthreads();
    if (t < ODIM) {
        float s4 = b4[t];
#pragma unroll 8
        for (int k = 0; k < ODIM; ++k) s4 += t1[k] * W4[k * ODIM + t];
        out[t] = s4;
    }
}

extern "C" void kernel_launch(void* const* d_in, const int* in_sizes, int n_in,
                              void* d_out, int out_size, void* d_ws, size_t ws_size,
                              hipStream_t stream) {
    const float* X  = (const float*)d_in[0];
    const float* W1 = (const float*)d_in[1];
    const float* b1 = (const float*)d_in[2];
    const float* W2 = (const float*)d_in[3];
    const float* b2 = (const float*)d_in[4];
    const float* W3 = (const float*)d_in[5];
    const float* b3 = (const float*)d_in[6];
    const float* W4 = (const float*)d_in[7];
    const float* b4 = (const float*)d_in[8];
    float* out = (float*)d_out;

    char* ws = (char*)d_ws;
    _Float16* Aph     = (_Float16*)ws;                 // 512*256 fp16 = 256 KB
    _Float16* Bg      = (_Float16*)(ws + 262144);      // 32 jt * 8 KB = 256 KB
    _Float16* W2g     = (_Float16*)(ws + 524288);      // 4 cg * 16 KB = 64 KB
    float*    partial = (float*)(ws + 589824);         // 512*32 f32 = 64 KB
    // total ws use < 1 MB

    kAW<<<144, 256, 0, stream>>>(X, W1, b1, Aph, Bg, W2, W2g);
    kB<<<512, 256, 0, stream>>>(Aph, Bg, W2g, b2, partial);
    kRC<<<1, 256, 0, stream>>>(partial, W3, b3, W4, b4, out);
}